// Round 9
// baseline (259.963 us; speedup 1.0000x reference)
//
#include <hip/hip_runtime.h>
#include <hip/hip_bf16.h>
#include <cstdint>
#include <cstddef>

// Problem constants (fixed by the reference):
#define HD   1024            // hidden H
#define NK   4               // heads K
#define DD   512             // H/2
#define LSEQ 2048            // L
#define NB   16              // B
#define MTOT (NB*LSEQ)       // 32768 tokens
#define NF2  (NK*DD)         // 2048 fused width (4 heads x 512)

typedef __attribute__((ext_vector_type(4))) float f32x4;
typedef __attribute__((ext_vector_type(8))) short bf16x8;

// async global->LDS, 16B per lane; LDS dest is wave-uniform base + lane*16
#define GLOAD16(gp, lp) __builtin_amdgcn_global_load_lds( \
    (const __attribute__((address_space(1))) void*)(gp),  \
    (__attribute__((address_space(3))) void*)(lp), 16, 0, 0)

static __device__ __forceinline__ ushort f2bf(float f) {
  union { float f; unsigned u; } x; x.f = f;
  unsigned r = x.u + 0x7FFFu + ((x.u >> 16) & 1u);   // RNE
  return (ushort)(r >> 16);
}

static __device__ __forceinline__ float fast_tanh(float x) {
  x = fminf(fmaxf(x, -15.f), 15.f);
  float t = __expf(2.0f * x);
  return (t - 1.0f) / (t + 1.0f);
}

// ---------------------------------------------------------------------------
__global__ void detect_mask_kernel(const unsigned char* __restrict__ m, int nbytes,
                                   int* __restrict__ flag) {
  int found = 0;
  for (int i = blockIdx.x * blockDim.x + threadIdx.x; i < nbytes;
       i += gridDim.x * blockDim.x)
    if ((i & 3) && m[i]) found = 1;
  if (__any(found) && (threadIdx.x & 63) == 0) atomicOr(flag, 1);
}

// ---------------------------------------------------------------------------
__global__ void cvt_f32_bf16_kernel(const float* __restrict__ src,
                                    ushort* __restrict__ dst, long n) {
  long stride = (long)gridDim.x * blockDim.x * 4;
  for (long i = ((long)blockIdx.x * blockDim.x + threadIdx.x) * 4; i < n; i += stride) {
    f32x4 v = *(const f32x4*)(src + i);
    ushort4 o; o.x = f2bf(v.x); o.y = f2bf(v.y); o.z = f2bf(v.z); o.w = f2bf(v.w);
    *(ushort4*)(dst + i) = o;
  }
}

// WpH[h][c][j] = bf16(Wp[c][h*1024 + j]);  4M elements, 4 per thread
__global__ void cvt_wp_heads_kernel(const float* __restrict__ Wp,
                                    ushort* __restrict__ WpH) {
  long i4 = ((long)blockIdx.x * blockDim.x + threadIdx.x) * 4;  // < 4*1024*1024
  int h = (int)(i4 >> 20);
  int c = (int)((i4 >> 10) & 1023);
  int j = (int)(i4 & 1023);
  f32x4 v = *(const f32x4*)(Wp + (long)c * (NK * HD) + h * HD + j);
  ushort4 o; o.x = f2bf(v.x); o.y = f2bf(v.y); o.z = f2bf(v.z); o.w = f2bf(v.w);
  *(ushort4*)(WpH + i4) = o;
}

// dst[c][r] = bf16(src[r][c]); grid.z = batch
__global__ void transpose_cvt_kernel(const float* __restrict__ src,
                                     ushort* __restrict__ dst,
                                     int R, int C, long sBatch, long dBatch) {
  __shared__ float tile[32][33];
  const float* s = src + blockIdx.z * sBatch;
  ushort* d = dst + blockIdx.z * dBatch;
  int c0 = blockIdx.x * 32, r0 = blockIdx.y * 32;
  int tx = threadIdx.x, ty = threadIdx.y;  // (32, 8)
  #pragma unroll
  for (int i = 0; i < 32; i += 8)
    tile[ty + i][tx] = s[(long)(r0 + ty + i) * C + (c0 + tx)];
  __syncthreads();
  #pragma unroll
  for (int i = 0; i < 32; i += 8)
    d[(long)(c0 + ty + i) * R + (r0 + tx)] = f2bf(tile[tx][ty + i]);
}

// ---------------------------------------------------------------------------
// Round-2 schedule: 256x256 tile, BK=32 slots, 4 sub-phases per K-tile of 64:
// {ds_read cur frags (compiler-managed lgkm); stage 1 slot-half; barrier;
//  setprio(1); 16 MFMA; setprio(0); [odd q: vmcnt(4)]; barrier}.
// 4-slot LDS ring per operand (16KB slots). 8 waves (2Mx4N), wave = 128x64 out.
// A: [M,lda] bf16 row-major (+z*aZs). Bt: [N,ldb] bf16 row-major (+z*bZs).
// MODE 0: Cout[z*cZs + row*ldc + col] = bf16(acc)
// MODE 1: CONTENTION-FREE partial store:
//   partial[(col>>6)][m0glob+row] = sum over wave's 64 cols of tanh(acc+b1)*W2
//   (each wslice = col/64 owned by exactly one wave of one block -> plain store)
template<int MODE>
__global__ __launch_bounds__(512, 2)
void gemm256_kernel(const ushort* __restrict__ A, int lda, long aZs,
                    const ushort* __restrict__ Bt, int ldb, long bZs, int Kdim,
                    ushort* __restrict__ Cout, int ldc, long cZs,
                    const float* __restrict__ b1, const float* __restrict__ W2,
                    float* __restrict__ partialOut, int m0glob) {
  // A slots: 4 x 16KB at [0..65536); B slots: 4 x 16KB at [65536..131072)
  __shared__ __align__(16) char lds[131072];

  const int tid = threadIdx.x;
  const int w = tid >> 6, lane = tid & 63;
  const int z = blockIdx.z;

  // XCD-aware swizzle of linear block id (bijective only when nwg%8==0)
  int bid = blockIdx.x + gridDim.x * blockIdx.y;
  const int nwg = gridDim.x * gridDim.y;
  if ((nwg & 7) == 0) {
    const int q = nwg >> 3;
    bid = (bid & 7) * q + (bid >> 3);
  }
  const int nMB = gridDim.x;
  const int m0 = (bid % nMB) * 256;
  const int n0 = (bid / nMB) * 256;

  const ushort* Ag = A + z * aZs + (long)m0 * lda;
  const ushort* Bg = Bt + z * bZs + (long)n0 * ldb;

  // wave tile: wm in {0,1} -> 128 M-rows; wn in {0..3} -> 64 N-cols
  const int wm = w >> 2, wn = w & 3;
  const int rsel = lane & 15;
  // read-side swizzle: chunk ^= (row>>1)&3 ; lane-constant since frag bases %16==0
  const int chunkC = ((lane >> 4) ^ ((rsel >> 1) & 3)) << 4;
  const int laneA = wm * 8192 + rsel * 64 + chunkC;           // + mh*4096 + mf*1024
  const int laneB = 65536 + wn * 4096 + rsel * 64 + chunkC;   // + nf*1024

  // staging: thread issues 2 x 16B per STAGE; linear LDS dest,
  // inverse-swizzled global col chunk
  const int stCg = ((lane & 3) ^ ((lane >> 3) & 3)) * 8;      // global col chunk (elems)
  const int stR0 = (w * 2) * 16 + (lane >> 2);                // rows: stR0, stR0+16
  const int stDst0 = (w * 2) * 1024;                          // + j*1024

  // stage K-half kh of K-tile ktile into slot dsl of region regionByte
  #define STAGE(gbase, ld, regionByte, dsl, ktile, kh)                          \
    {                                                                           \
      _Pragma("unroll")                                                         \
      for (int j = 0; j < 2; ++j) {                                             \
        const ushort* gp = (gbase) + (long)(stR0 + j * 16) * (ld) +             \
                           ((ktile) << 6) + ((kh) << 5) + stCg;                 \
        GLOAD16(gp, lds + (regionByte) + (dsl) * 16384 + stDst0 + j * 1024);    \
      }                                                                         \
    }

  f32x4 acc[8][4] = {};

  // prologue: stage K-tile 0 into slots 0 (kh0) and 1 (kh1)
  STAGE(Ag, lda, 0,     0, 0, 0);
  STAGE(Bg, ldb, 65536, 0, 0, 0);
  STAGE(Ag, lda, 0,     1, 0, 1);
  STAGE(Bg, ldb, 65536, 1, 0, 1);
  asm volatile("s_waitcnt vmcnt(4)" ::: "memory");  // A0,B0 of slot 0 landed
  __builtin_amdgcn_sched_barrier(0);
  __builtin_amdgcn_s_barrier();

  const int nt = Kdim >> 6;   // K-tiles of 64
  for (int t = 0; t < nt; ++t) {
    const int ts = (t + 1 < nt) ? t + 1 : t;              // clamped prefetch tile
    const int s0 = (2 * t) & 3, s1 = (2 * t + 1) & 3;     // compute slots (kh0, kh1)
    const int p0 = (2 * t + 2) & 3, p1 = (2 * t + 3) & 3; // prefetch dest slots
    bf16x8 aF[4], bB[4];
    #pragma unroll
    for (int q = 0; q < 4; ++q) {
      const int kk = q >> 1, mh = q & 1;
      const int slot = (kk ? s1 : s0) * 16384;
      if (mh == 0) {
        #pragma unroll
        for (int nf = 0; nf < 4; ++nf)
          bB[nf] = *(const bf16x8*)(lds + slot + laneB + nf * 1024);
      }
      #pragma unroll
      for (int mf = 0; mf < 4; ++mf)
        aF[mf] = *(const bf16x8*)(lds + slot + laneA + mh * 4096 + mf * 1024);
      if (q == 0)      STAGE(Ag, lda, 0,     p0, ts, 0)
      else if (q == 1) STAGE(Bg, ldb, 65536, p0, ts, 0)
      else if (q == 2) STAGE(Ag, lda, 0,     p1, ts, 1)
      else             STAGE(Bg, ldb, 65536, p1, ts, 1)
      __builtin_amdgcn_s_barrier();
      __builtin_amdgcn_s_setprio(1);
      #pragma unroll
      for (int mf = 0; mf < 4; ++mf)
        #pragma unroll
        for (int nf = 0; nf < 4; ++nf)
          acc[mh * 4 + mf][nf] = __builtin_amdgcn_mfma_f32_16x16x32_bf16(
              aF[mf], bB[nf], acc[mh * 4 + mf][nf], 0, 0, 0);
      __builtin_amdgcn_s_setprio(0);
      if (q & 1) {
        asm volatile("s_waitcnt vmcnt(4)" ::: "memory");
        __builtin_amdgcn_sched_barrier(0);
      }
      __builtin_amdgcn_s_barrier();
    }
  }
  asm volatile("s_waitcnt vmcnt(0)" ::: "memory");  // drain DMAs before exit

  if constexpr (MODE == 0) {
    #pragma unroll
    for (int mf = 0; mf < 8; ++mf)
      #pragma unroll
      for (int nf = 0; nf < 4; ++nf) {
        const int col = n0 + wn * 64 + nf * 16 + (lane & 15);
        #pragma unroll
        for (int r = 0; r < 4; ++r) {
          const int row = m0 + wm * 128 + mf * 16 + ((lane >> 4) << 2) + r;
          Cout[z * cZs + (long)row * ldc + col] = f2bf(acc[mf][nf][r]);
        }
      }
  } else {
    float b1v[4], w2v[4];
    #pragma unroll
    for (int nf = 0; nf < 4; ++nf) {
      const int col = n0 + wn * 64 + nf * 16 + (lane & 15);
      b1v[nf] = b1[col];
      w2v[nf] = W2[col];
    }
    // wslice = (first col of this wave)/64 ; disjoint across all waves/blocks
    const int wslice = (n0 + wn * 64) >> 6;
    float* pb = partialOut + (long)wslice * MTOT + m0glob + m0 + wm * 128;
    #pragma unroll
    for (int mf = 0; mf < 8; ++mf)
      #pragma unroll
      for (int r = 0; r < 4; ++r) {
        float s = 0.f;
        #pragma unroll
        for (int nf = 0; nf < 4; ++nf)
          s += fast_tanh(acc[mf][nf][r] + b1v[nf]) * w2v[nf];
        s += __shfl_xor(s, 1, 64);
        s += __shfl_xor(s, 2, 64);
        s += __shfl_xor(s, 4, 64);
        s += __shfl_xor(s, 8, 64);
        if ((lane & 15) == 0)
          pb[mf * 16 + ((lane >> 4) << 2) + r] = s;   // plain store, no atomic
      }
  }
  #undef STAGE
}

// ---------------------------------------------------------------------------
// masked softmax over L per (k,b) row; sums 8 col-slices per head first.
// partial: [32][MTOT] f32, wslice ws covers cols ws*64..ws*64+63; head = ws>>3.
__global__ __launch_bounds__(256)
void masked_softmax_kernel(const float* __restrict__ partial,
                           const unsigned char* __restrict__ maskB,
                           const int* __restrict__ maskI,
                           const int* __restrict__ flag,
                           float* __restrict__ out) {
  const int kb = blockIdx.x;          // k*NB + b
  const int k = kb >> 4, b = kb & (NB - 1);
  const long base = (long)kb * LSEQ;
  const bool isByte = (*flag != 0);
  const int tid = threadIdx.x;
  const float* pk = partial + (long)(k * 8) * MTOT + (long)b * LSEQ;

  float x[8];
  float mx = -3.0e38f;
  #pragma unroll
  for (int j = 0; j < 8; ++j) {
    int l = tid + j * 256;
    float v = 0.f;
    #pragma unroll
    for (int ws = 0; ws < 8; ++ws) v += pk[(long)ws * MTOT + l];
    bool msk = isByte ? (maskB[b * LSEQ + l] != 0) : (maskI[b * LSEQ + l] != 0);
    v = msk ? -1e9f : v;
    x[j] = v; mx = fmaxf(mx, v);
  }
  __shared__ float redm[4], reds[4];
  #pragma unroll
  for (int off = 32; off >= 1; off >>= 1) mx = fmaxf(mx, __shfl_xor(mx, off, 64));
  if ((tid & 63) == 0) redm[tid >> 6] = mx;
  __syncthreads();
  mx = fmaxf(fmaxf(redm[0], redm[1]), fmaxf(redm[2], redm[3]));

  float sum = 0.f;
  #pragma unroll
  for (int j = 0; j < 8; ++j) { x[j] = __expf(x[j] - mx); sum += x[j]; }
  #pragma unroll
  for (int off = 32; off >= 1; off >>= 1) sum += __shfl_xor(sum, off, 64);
  if ((tid & 63) == 0) reds[tid >> 6] = sum;
  __syncthreads();
  sum = reds[0] + reds[1] + reds[2] + reds[3];

  float inv = 1.0f / sum;
  #pragma unroll
  for (int j = 0; j < 8; ++j) out[base + tid + j * 256] = x[j] * inv;
}

// ---------------------------------------------------------------------------
extern "C" void kernel_launch(void* const* d_in, const int* in_sizes, int n_in,
                              void* d_out, int out_size, void* d_ws, size_t ws_size,
                              hipStream_t stream) {
  const float* hidden = (const float*)d_in[0];
  const void*  masks  = d_in[1];
  const float* Wp     = (const float*)d_in[2];
  const float* W1     = (const float*)d_in[3];
  const float* b1     = (const float*)d_in[4];
  const float* W2     = (const float*)d_in[5];
  float* out = (float*)d_out;

  // workspace layout (bytes)
  char* ws = (char*)d_ws;
  ushort* W1T      = (ushort*)(ws + 0);                 //  4,194,304  [4][512][1024] bf16
  ushort* WpH      = (ushort*)(ws + 4194304);           //  8,388,608  [4][1024][1024] bf16
  ushort* WfT      = (ushort*)(ws + 12582912);          //  4,194,304  [2048][1024] bf16
  float*  partial  = (float*) (ws + 16777216);          //  4,194,304  [32][32768] f32
  int*    flag     = (int*)   (ws + 20971520);          //        256
  ushort* hiddenBf = (ushort*)(ws + 20971776);          // chunkM*2048 bytes

  const size_t fixedBytes = 20971776;
  size_t avail = (ws_size > fixedBytes) ? (ws_size - fixedBytes) : 0;
  long chunkM = (long)(avail / ((long)HD * 2)) & ~255L;
  if (chunkM > MTOT) chunkM = MTOT;
  if (chunkM < 256) chunkM = 256;  // requires ws_size >= ~21.5 MB

  hipMemsetAsync(flag, 0, 256, stream);

  detect_mask_kernel<<<8, 256, 0, stream>>>((const unsigned char*)masks, NB * LSEQ, flag);

  // W1T[h][d][j] = bf16(W1[h][j][d])
  dim3 tb(32, 8);
  transpose_cvt_kernel<<<dim3(DD / 32, HD / 32, NK), tb, 0, stream>>>(
      W1, W1T, HD, DD, (long)HD * DD, (long)DD * HD);
  // WpH[h][c][j] = bf16(Wp[c][h*1024+j])
  cvt_wp_heads_kernel<<<4096, 256, 0, stream>>>(Wp, WpH);

  // WfT[h*512+d][c] = sum_j W1T[h][d][j] * WpH[h][c][j]   (= (Wp@W1)^T per head)
  gemm256_kernel<0><<<dim3(2, 4, 4), 512, 0, stream>>>(
      W1T, HD, (long)DD * HD,
      WpH, HD, (long)HD * HD, HD,
      WfT, HD, (long)DD * HD,
      nullptr, nullptr, nullptr, 0);

  for (long m0 = 0; m0 < MTOT; m0 += chunkM) {
    long cm = chunkM; if (m0 + cm > MTOT) cm = MTOT - m0;
    cvt_f32_bf16_kernel<<<2048, 256, 0, stream>>>(
        hidden + m0 * HD, hiddenBf, cm * HD);
    // partial[col/64][m0+row] = sum over 64 cols of tanh(hidden@WfT^T + b1)*W2
    gemm256_kernel<1><<<dim3(cm / 256, NF2 / 256, 1), 512, 0, stream>>>(
        hiddenBf, HD, 0,
        WfT, HD, 0, HD,
        nullptr, 0, 0,
        b1, W2, partial, (int)m0);
  }

  masked_softmax_kernel<<<NK * NB, 256, 0, stream>>>(
      partial, (const unsigned char*)masks, (const int*)masks, flag, out);
}

// Round 10
// 252.671 us; speedup vs baseline: 1.0289x; 1.0289x over previous
//
#include <hip/hip_runtime.h>
#include <hip/hip_bf16.h>
#include <cstdint>
#include <cstddef>

// Problem constants (fixed by the reference):
#define HD   1024            // hidden H
#define NK   4               // heads K
#define DD   512             // H/2
#define LSEQ 2048            // L
#define NB   16              // B
#define MTOT (NB*LSEQ)       // 32768 tokens
#define NF2  (NK*DD)         // 2048 fused width (4 heads x 512)

typedef __attribute__((ext_vector_type(4))) float f32x4;
typedef __attribute__((ext_vector_type(8))) short bf16x8;

// async global->LDS, 16B per lane; LDS dest is wave-uniform base + lane*16
#define GLOAD16(gp, lp) __builtin_amdgcn_global_load_lds( \
    (const __attribute__((address_space(1))) void*)(gp),  \
    (__attribute__((address_space(3))) void*)(lp), 16, 0, 0)

static __device__ __forceinline__ ushort f2bf(float f) {
  union { float f; unsigned u; } x; x.f = f;
  unsigned r = x.u + 0x7FFFu + ((x.u >> 16) & 1u);   // RNE
  return (ushort)(r >> 16);
}

static __device__ __forceinline__ float fast_tanh(float x) {
  x = fminf(fmaxf(x, -15.f), 15.f);
  float t = __expf(2.0f * x);
  return (t - 1.0f) / (t + 1.0f);
}

// ---------------------------------------------------------------------------
__global__ void detect_mask_kernel(const unsigned char* __restrict__ m, int nbytes,
                                   int* __restrict__ flag) {
  int found = 0;
  for (int i = blockIdx.x * blockDim.x + threadIdx.x; i < nbytes;
       i += gridDim.x * blockDim.x)
    if ((i & 3) && m[i]) found = 1;
  if (__any(found) && (threadIdx.x & 63) == 0) atomicOr(flag, 1);
}

// ---------------------------------------------------------------------------
__global__ void cvt_f32_bf16_kernel(const float* __restrict__ src,
                                    ushort* __restrict__ dst, long n) {
  long stride = (long)gridDim.x * blockDim.x * 4;
  for (long i = ((long)blockIdx.x * blockDim.x + threadIdx.x) * 4; i < n; i += stride) {
    f32x4 v = *(const f32x4*)(src + i);
    ushort4 o; o.x = f2bf(v.x); o.y = f2bf(v.y); o.z = f2bf(v.z); o.w = f2bf(v.w);
    *(ushort4*)(dst + i) = o;
  }
}

// WpH[h][c][j] = bf16(Wp[c][h*1024 + j]);  4M elements, 4 per thread
__global__ void cvt_wp_heads_kernel(const float* __restrict__ Wp,
                                    ushort* __restrict__ WpH) {
  long i4 = ((long)blockIdx.x * blockDim.x + threadIdx.x) * 4;  // < 4*1024*1024
  int h = (int)(i4 >> 20);
  int c = (int)((i4 >> 10) & 1023);
  int j = (int)(i4 & 1023);
  f32x4 v = *(const f32x4*)(Wp + (long)c * (NK * HD) + h * HD + j);
  ushort4 o; o.x = f2bf(v.x); o.y = f2bf(v.y); o.z = f2bf(v.z); o.w = f2bf(v.w);
  *(ushort4*)(WpH + i4) = o;
}

// dst[c][r] = bf16(src[r][c]); grid.z = batch
__global__ void transpose_cvt_kernel(const float* __restrict__ src,
                                     ushort* __restrict__ dst,
                                     int R, int C, long sBatch, long dBatch) {
  __shared__ float tile[32][33];
  const float* s = src + blockIdx.z * sBatch;
  ushort* d = dst + blockIdx.z * dBatch;
  int c0 = blockIdx.x * 32, r0 = blockIdx.y * 32;
  int tx = threadIdx.x, ty = threadIdx.y;  // (32, 8)
  #pragma unroll
  for (int i = 0; i < 32; i += 8)
    tile[ty + i][tx] = s[(long)(r0 + ty + i) * C + (c0 + tx)];
  __syncthreads();
  #pragma unroll
  for (int i = 0; i < 32; i += 8)
    d[(long)(c0 + ty + i) * R + (r0 + tx)] = f2bf(tile[tx][ty + i]);
}

// ---------------------------------------------------------------------------
// Round-2 schedule: 256x256 tile, BK=32 slots, 4 sub-phases per K-tile of 64:
// {ds_read cur frags (compiler-managed lgkm); stage 1 slot-half; barrier;
//  setprio(1); 16 MFMA; setprio(0); [odd q: vmcnt(4)]; barrier}.
// 4-slot LDS ring per operand (16KB slots). 8 waves (2Mx4N), wave = 128x64 out.
// SUPERTILE XCD MAPPING (new): HW dispatches bid round-robin over 8 XCDs, so
// xcd = bid&7, j = bid>>3. XCD x owns m-strip [x*nMB/8, (x+1)*nMB/8) x all
// n-panels, n-fastest: co-resident 32 blocks/XCD = 4m x 8n rectangle ->
// A-panels shared 8-way, B-panels 4-way+persistent; working set ~ 4MB L2.
// A: [M,lda] bf16 row-major (+z*aZs). Bt: [N,ldb] bf16 row-major (+z*bZs).
// MODE 0: Cout[z*cZs + row*ldc + col] = bf16(acc)
// MODE 1: partial[(col>>6)][m0glob+row] = wave's 64-col sum of tanh(acc+b1)*W2
template<int MODE>
__global__ __launch_bounds__(512, 2)
void gemm256_kernel(const ushort* __restrict__ A, int lda, long aZs,
                    const ushort* __restrict__ Bt, int ldb, long bZs, int Kdim,
                    ushort* __restrict__ Cout, int ldc, long cZs,
                    const float* __restrict__ b1, const float* __restrict__ W2,
                    float* __restrict__ partialOut, int m0glob) {
  // A slots: 4 x 16KB at [0..65536); B slots: 4 x 16KB at [65536..131072)
  __shared__ __align__(16) char lds[131072];

  const int tid = threadIdx.x;
  const int w = tid >> 6, lane = tid & 63;
  const int z = blockIdx.z;

  // supertile XCD mapping (bijective when nMB%8==0); else legacy column-major
  const int bid = blockIdx.x + gridDim.x * blockIdx.y;
  const int nMB = gridDim.x, nNB = gridDim.y;
  int m0, n0;
  if ((nMB & 7) == 0) {
    const int x = bid & 7, j = bid >> 3;
    const int mi = x * (nMB >> 3) + j / nNB;
    const int ni = j % nNB;
    m0 = mi * 256; n0 = ni * 256;
  } else {
    m0 = (bid % nMB) * 256; n0 = (bid / nMB) * 256;
  }

  const ushort* Ag = A + z * aZs + (long)m0 * lda;
  const ushort* Bg = Bt + z * bZs + (long)n0 * ldb;

  // wave tile: wm in {0,1} -> 128 M-rows; wn in {0..3} -> 64 N-cols
  const int wm = w >> 2, wn = w & 3;
  const int rsel = lane & 15;
  // read-side swizzle: chunk ^= (row>>1)&3 ; lane-constant since frag bases %16==0
  const int chunkC = ((lane >> 4) ^ ((rsel >> 1) & 3)) << 4;
  const int laneA = wm * 8192 + rsel * 64 + chunkC;           // + mh*4096 + mf*1024
  const int laneB = 65536 + wn * 4096 + rsel * 64 + chunkC;   // + nf*1024

  // staging: thread issues 2 x 16B per STAGE; linear LDS dest,
  // inverse-swizzled global col chunk
  const int stCg = ((lane & 3) ^ ((lane >> 3) & 3)) * 8;      // global col chunk (elems)
  const int stR0 = (w * 2) * 16 + (lane >> 2);                // rows: stR0, stR0+16
  const int stDst0 = (w * 2) * 1024;                          // + j*1024

  // stage K-half kh of K-tile ktile into slot dsl of region regionByte
  #define STAGE(gbase, ld, regionByte, dsl, ktile, kh)                          \
    {                                                                           \
      _Pragma("unroll")                                                         \
      for (int jj = 0; jj < 2; ++jj) {                                          \
        const ushort* gp = (gbase) + (long)(stR0 + jj * 16) * (ld) +            \
                           ((ktile) << 6) + ((kh) << 5) + stCg;                 \
        GLOAD16(gp, lds + (regionByte) + (dsl) * 16384 + stDst0 + jj * 1024);   \
      }                                                                         \
    }

  f32x4 acc[8][4] = {};

  // prologue: stage K-tile 0 into slots 0 (kh0) and 1 (kh1)
  STAGE(Ag, lda, 0,     0, 0, 0);
  STAGE(Bg, ldb, 65536, 0, 0, 0);
  STAGE(Ag, lda, 0,     1, 0, 1);
  STAGE(Bg, ldb, 65536, 1, 0, 1);
  asm volatile("s_waitcnt vmcnt(4)" ::: "memory");  // A0,B0 of slot 0 landed
  __builtin_amdgcn_sched_barrier(0);
  __builtin_amdgcn_s_barrier();

  const int nt = Kdim >> 6;   // K-tiles of 64
  for (int t = 0; t < nt; ++t) {
    const int ts = (t + 1 < nt) ? t + 1 : t;              // clamped prefetch tile
    const int s0 = (2 * t) & 3, s1 = (2 * t + 1) & 3;     // compute slots (kh0, kh1)
    const int p0 = (2 * t + 2) & 3, p1 = (2 * t + 3) & 3; // prefetch dest slots
    bf16x8 aF[4], bB[4];
    #pragma unroll
    for (int q = 0; q < 4; ++q) {
      const int kk = q >> 1, mh = q & 1;
      const int slot = (kk ? s1 : s0) * 16384;
      if (mh == 0) {
        #pragma unroll
        for (int nf = 0; nf < 4; ++nf)
          bB[nf] = *(const bf16x8*)(lds + slot + laneB + nf * 1024);
      }
      #pragma unroll
      for (int mf = 0; mf < 4; ++mf)
        aF[mf] = *(const bf16x8*)(lds + slot + laneA + mh * 4096 + mf * 1024);
      if (q == 0)      STAGE(Ag, lda, 0,     p0, ts, 0)
      else if (q == 1) STAGE(Bg, ldb, 65536, p0, ts, 0)
      else if (q == 2) STAGE(Ag, lda, 0,     p1, ts, 1)
      else             STAGE(Bg, ldb, 65536, p1, ts, 1)
      __builtin_amdgcn_s_barrier();
      __builtin_amdgcn_s_setprio(1);
      #pragma unroll
      for (int mf = 0; mf < 4; ++mf)
        #pragma unroll
        for (int nf = 0; nf < 4; ++nf)
          acc[mh * 4 + mf][nf] = __builtin_amdgcn_mfma_f32_16x16x32_bf16(
              aF[mf], bB[nf], acc[mh * 4 + mf][nf], 0, 0, 0);
      __builtin_amdgcn_s_setprio(0);
      if (q & 1) {
        asm volatile("s_waitcnt vmcnt(4)" ::: "memory");
        __builtin_amdgcn_sched_barrier(0);
      }
      __builtin_amdgcn_s_barrier();
    }
  }
  asm volatile("s_waitcnt vmcnt(0)" ::: "memory");  // drain DMAs before exit

  if constexpr (MODE == 0) {
    #pragma unroll
    for (int mf = 0; mf < 8; ++mf)
      #pragma unroll
      for (int nf = 0; nf < 4; ++nf) {
        const int col = n0 + wn * 64 + nf * 16 + (lane & 15);
        #pragma unroll
        for (int r = 0; r < 4; ++r) {
          const int row = m0 + wm * 128 + mf * 16 + ((lane >> 4) << 2) + r;
          Cout[z * cZs + (long)row * ldc + col] = f2bf(acc[mf][nf][r]);
        }
      }
  } else {
    float b1v[4], w2v[4];
    #pragma unroll
    for (int nf = 0; nf < 4; ++nf) {
      const int col = n0 + wn * 64 + nf * 16 + (lane & 15);
      b1v[nf] = b1[col];
      w2v[nf] = W2[col];
    }
    // wslice = (first col of this wave)/64 ; disjoint across all waves/blocks
    const int wslice = (n0 + wn * 64) >> 6;
    float* pb = partialOut + (long)wslice * MTOT + m0glob + m0 + wm * 128;
    #pragma unroll
    for (int mf = 0; mf < 8; ++mf)
      #pragma unroll
      for (int r = 0; r < 4; ++r) {
        float s = 0.f;
        #pragma unroll
        for (int nf = 0; nf < 4; ++nf)
          s += fast_tanh(acc[mf][nf][r] + b1v[nf]) * w2v[nf];
        s += __shfl_xor(s, 1, 64);
        s += __shfl_xor(s, 2, 64);
        s += __shfl_xor(s, 4, 64);
        s += __shfl_xor(s, 8, 64);
        if ((lane & 15) == 0)
          pb[mf * 16 + ((lane >> 4) << 2) + r] = s;   // plain store, no atomic
      }
  }
  #undef STAGE
}

// ---------------------------------------------------------------------------
// masked softmax over L per (k,b) row; sums 8 col-slices per head first.
// partial: [32][MTOT] f32, wslice ws covers cols ws*64..ws*64+63; head = ws>>3.
__global__ __launch_bounds__(256)
void masked_softmax_kernel(const float* __restrict__ partial,
                           const unsigned char* __restrict__ maskB,
                           const int* __restrict__ maskI,
                           const int* __restrict__ flag,
                           float* __restrict__ out) {
  const int kb = blockIdx.x;          // k*NB + b
  const int k = kb >> 4, b = kb & (NB - 1);
  const long base = (long)kb * LSEQ;
  const bool isByte = (*flag != 0);
  const int tid = threadIdx.x;
  const float* pk = partial + (long)(k * 8) * MTOT + (long)b * LSEQ;

  float x[8];
  float mx = -3.0e38f;
  #pragma unroll
  for (int j = 0; j < 8; ++j) {
    int l = tid + j * 256;
    float v = 0.f;
    #pragma unroll
    for (int ws = 0; ws < 8; ++ws) v += pk[(long)ws * MTOT + l];
    bool msk = isByte ? (maskB[b * LSEQ + l] != 0) : (maskI[b * LSEQ + l] != 0);
    v = msk ? -1e9f : v;
    x[j] = v; mx = fmaxf(mx, v);
  }
  __shared__ float redm[4], reds[4];
  #pragma unroll
  for (int off = 32; off >= 1; off >>= 1) mx = fmaxf(mx, __shfl_xor(mx, off, 64));
  if ((tid & 63) == 0) redm[tid >> 6] = mx;
  __syncthreads();
  mx = fmaxf(fmaxf(redm[0], redm[1]), fmaxf(redm[2], redm[3]));

  float sum = 0.f;
  #pragma unroll
  for (int j = 0; j < 8; ++j) { x[j] = __expf(x[j] - mx); sum += x[j]; }
  #pragma unroll
  for (int off = 32; off >= 1; off >>= 1) sum += __shfl_xor(sum, off, 64);
  if ((tid & 63) == 0) reds[tid >> 6] = sum;
  __syncthreads();
  sum = reds[0] + reds[1] + reds[2] + reds[3];

  float inv = 1.0f / sum;
  #pragma unroll
  for (int j = 0; j < 8; ++j) out[base + tid + j * 256] = x[j] * inv;
}

// ---------------------------------------------------------------------------
extern "C" void kernel_launch(void* const* d_in, const int* in_sizes, int n_in,
                              void* d_out, int out_size, void* d_ws, size_t ws_size,
                              hipStream_t stream) {
  const float* hidden = (const float*)d_in[0];
  const void*  masks  = d_in[1];
  const float* Wp     = (const float*)d_in[2];
  const float* W1     = (const float*)d_in[3];
  const float* b1     = (const float*)d_in[4];
  const float* W2     = (const float*)d_in[5];
  float* out = (float*)d_out;

  // workspace layout (bytes)
  char* ws = (char*)d_ws;
  ushort* W1T      = (ushort*)(ws + 0);                 //  4,194,304  [4][512][1024] bf16
  ushort* WpH      = (ushort*)(ws + 4194304);           //  8,388,608  [4][1024][1024] bf16
  ushort* WfT      = (ushort*)(ws + 12582912);          //  4,194,304  [2048][1024] bf16
  float*  partial  = (float*) (ws + 16777216);          //  4,194,304  [32][32768] f32
  int*    flag     = (int*)   (ws + 20971520);          //        256
  ushort* hiddenBf = (ushort*)(ws + 20971776);          // chunkM*2048 bytes

  const size_t fixedBytes = 20971776;
  size_t avail = (ws_size > fixedBytes) ? (ws_size - fixedBytes) : 0;
  long chunkM = (long)(avail / ((long)HD * 2)) & ~255L;
  if (chunkM > MTOT) chunkM = MTOT;
  if (chunkM < 256) chunkM = 256;  // requires ws_size >= ~21.5 MB

  hipMemsetAsync(flag, 0, 256, stream);

  detect_mask_kernel<<<8, 256, 0, stream>>>((const unsigned char*)masks, NB * LSEQ, flag);

  // W1T[h][d][j] = bf16(W1[h][j][d])
  dim3 tb(32, 8);
  transpose_cvt_kernel<<<dim3(DD / 32, HD / 32, NK), tb, 0, stream>>>(
      W1, W1T, HD, DD, (long)HD * DD, (long)DD * HD);
  // WpH[h][c][j] = bf16(Wp[c][h*1024+j])
  cvt_wp_heads_kernel<<<4096, 256, 0, stream>>>(Wp, WpH);

  // WfT[h*512+d][c] = sum_j W1T[h][d][j] * WpH[h][c][j]   (= (Wp@W1)^T per head)
  gemm256_kernel<0><<<dim3(2, 4, 4), 512, 0, stream>>>(
      W1T, HD, (long)DD * HD,
      WpH, HD, (long)HD * HD, HD,
      WfT, HD, (long)DD * HD,
      nullptr, nullptr, nullptr, 0);

  for (long m0 = 0; m0 < MTOT; m0 += chunkM) {
    long cm = chunkM; if (m0 + cm > MTOT) cm = MTOT - m0;
    cvt_f32_bf16_kernel<<<2048, 256, 0, stream>>>(
        hidden + m0 * HD, hiddenBf, cm * HD);
    // partial[col/64][m0+row] = sum over 64 cols of tanh(hidden@WfT^T + b1)*W2
    gemm256_kernel<1><<<dim3(cm / 256, NF2 / 256, 1), 512, 0, stream>>>(
        hiddenBf, HD, 0,
        WfT, HD, 0, HD,
        nullptr, 0, 0,
        b1, W2, partial, (int)m0);
  }

  masked_softmax_kernel<<<NK * NB, 256, 0, stream>>>(
      partial, (const unsigned char*)masks, (const int*)masks, flag, out);
}